// Round 7
// baseline (121.945 us; speedup 1.0000x reference)
//
#include <hip/hip_runtime.h>
#include <hip/hip_bf16.h>

// FConv2d exact reduced form:
// out[b, d*16+n, r, s] =
//   0.5 * sum_{c2<32,u,v<3} W[n,c2,2-u,2-v] * (xa + xb)[r+u, s+v]
// xa = x[b,(8d-c2)%128], xb = x[b,(-8d-c2)%128], zero outside 32x32;
// xcomb[16-d] == xcomb[d]  =>  compute d=0..8, mirror-write 9..15.
// (Verified: r3 fp32 7.8e-3, r4/r5/r6 bf16-MFMA 1.56e-2 vs np ref.)
//
// ROUND 7 = CALIBRATION PROBE: the round-6 kernel launched 4x back-to-back
// (identical dispatches, idempotent). bench = floor + 4k vs round-6's
// floor + k = 79.4 us  =>  k = (bench - 79.4)/3. Distinguishes
// H1 (kernel ~29 us -> bench ~166) from H2 (kernel ~5 us, harness floor
// ~75 -> bench ~93). Three different kernels at 79-80 us demand this
// measurement before further edits.

typedef __attribute__((ext_vector_type(8))) short short8;
typedef __attribute__((ext_vector_type(4))) float floatx4;

#define NT 256
#define SROW 34              // xs row stride in 16-B granules
#define SOCT (10 * SROW)     // 340 granules per c2-octet

static __device__ __forceinline__ short bf16bits(float f) {
    __hip_bfloat16 h = __float2bfloat16(f);
    return __builtin_bit_cast(short, h);
}

__global__ __launch_bounds__(NT, 4)
void fconv_mfma(const float* __restrict__ x,
                const float* __restrict__ wgt,
                float* __restrict__ out) {
    __shared__ __align__(16) short xs[4 * 10 * SROW * 8];   // 21760 B
    __shared__ __align__(16) short wf[9 * 16 * 32];         //  9216 B

    const int quarter = blockIdx.x;   // 0..3 : 8-row band
    const int d       = blockIdx.y;   // 0..8
    const int b       = blockIdx.z;   // 0..15
    const int r0      = quarter * 8;
    const int tid     = threadIdx.x;
    const int dup     = ((d & 7) == 0);   // d==0 or d==8: xa == xb

    const float* xb_base = x + ((size_t)b << 17);   // b*128*1024

    // ---- weights -> LDS: wf[t][n][c2] = W[n][c2][flip(t)], t=8-k ----
#pragma unroll
    for (int pp = 0; pp < 2; ++pp) {
        const int p  = tid + pp * NT;      // 0..511
        const int n  = p >> 5;
        const int c2 = p & 31;
        const float* wb = wgt + (size_t)(n * 32 + c2) * 9;
#pragma unroll
        for (int k = 0; k < 9; ++k)
            wf[(8 - k) * 512 + n * 32 + c2] = bf16bits(wb[k]);
    }

    // ---- stage xcomb granules: 1280 tasks (oct, r, s) ----
#pragma unroll
    for (int it = 0; it < 5; ++it) {
        const int task = tid + it * NT;       // 0..1279
        const int oct  = task / 320;          // wave-uniform (320 % 64 == 0)
        const int rem  = task - oct * 320;
        const int r    = rem >> 5;            // 0..9
        const int s    = rem & 31;
        const int gr   = r0 + r;
        short8 g;
        if (gr < 32) {
            const int off = (gr << 5) + s;
#pragma unroll
            for (int j = 0; j < 8; ++j) {
                const int c2  = oct * 8 + j;
                const int c1a = (8 * d - c2) & 127;
                const float va = xb_base[(c1a << 10) + off];
                float v;
                if (dup) {
                    v = va;
                } else {
                    const int c1b = (-8 * d - c2) & 127;
                    const float vb = xb_base[(c1b << 10) + off];
                    v = 0.5f * (va + vb);
                }
                g[j] = bf16bits(v);
            }
        } else {
#pragma unroll
            for (int j = 0; j < 8; ++j) g[j] = 0;
        }
        *(short8*)&xs[(oct * SOCT + r * SROW + s) << 3] = g;
    }
    // s-apron (s = 32, 33) zeros
    if (tid < 80) {
        const int oct = tid / 20;
        const int rem = tid - oct * 20;
        const int r   = rem >> 1;
        const int s   = 32 + (rem & 1);
        short8 z = {0, 0, 0, 0, 0, 0, 0, 0};
        *(short8*)&xs[(oct * SOCT + r * SROW + s) << 3] = z;
    }

    __syncthreads();

    // ---- A fragments from LDS: 9 conflict-free ds_read_b128 ----
    const int lane = tid & 63;
    const int c    = lane & 15;     // A: n index; B/D: col (s offset)
    const int q    = lane >> 4;     // k-octet; D: row group (n = q*4+reg)
    short8 af[9];
#pragma unroll
    for (int t = 0; t < 9; ++t)
        af[t] = *(const short8*)&wf[t * 512 + c * 32 + q * 8];

    // ---- compute: wave w does 4 tiles (2 rows x 2 col-halves) ----
    const int w = tid >> 6;
#pragma unroll
    for (int i = 0; i < 4; ++i) {
        const int lr = 2 * w + (i >> 1);      // local output row 0..7
        const int s0 = (i & 1) << 4;          // 0 or 16
        floatx4 acc = {0.f, 0.f, 0.f, 0.f};
        const short* basep = &xs[(q * SOCT + lr * SROW + s0 + c) << 3];
#pragma unroll
        for (int u = 0; u < 3; ++u)
#pragma unroll
            for (int v = 0; v < 3; ++v) {
                const short8 bf = *(const short8*)(basep + ((u * SROW + v) << 3));
                acc = __builtin_amdgcn_mfma_f32_16x16x32_bf16(af[u * 3 + v], bf, acc, 0, 0, 0);
            }
        // D: col = c (s = s0+c), row = q*4+reg (n)
        float* op = out + (size_t)(((b * 256 + d * 16 + q * 4) * 32 + (r0 + lr)) * 32 + s0 + c);
        op[0]    = acc.x;
        op[1024] = acc.y;
        op[2048] = acc.z;
        op[3072] = acc.w;
        if (d >= 1 && d <= 7) {   // mirror channel group (16-d)
            float* op2 = out + (size_t)(((b * 256 + (16 - d) * 16 + q * 4) * 32 + (r0 + lr)) * 32 + s0 + c);
            op2[0]    = acc.x;
            op2[1024] = acc.y;
            op2[2048] = acc.z;
            op2[3072] = acc.w;
        }
    }
}

extern "C" void kernel_launch(void* const* d_in, const int* in_sizes, int n_in,
                              void* d_out, int out_size, void* d_ws, size_t ws_size,
                              hipStream_t stream) {
    const float* x   = (const float*)d_in[0];   // (16,128,32,32) fp32
    const float* wgt = (const float*)d_in[1];   // (16,32,3,3)   fp32
    float* out = (float*)d_out;                 // (16,256,32,32) fp32
    (void)in_sizes; (void)n_in; (void)out_size; (void)d_ws; (void)ws_size;

    dim3 grid(4, 9, 16);    // (quarter-band, d=0..8, b)
    dim3 block(NT);
    // CALIBRATION: 4 identical idempotent dispatches; bench = floor + 4k.
    for (int rep = 0; rep < 4; ++rep)
        fconv_mfma<<<grid, block, 0, stream>>>(x, wgt, out);
}

// Round 8
// 81.440 us; speedup vs baseline: 1.4974x; 1.4974x over previous
//
#include <hip/hip_runtime.h>
#include <hip/hip_bf16.h>

// FConv2d exact reduced form:
// out[b, d*16+n, r, s] =
//   0.5 * sum_{c2<32,u,v<3} W[n,c2,2-u,2-v] * (xa + xb)[r+u, s+v]
// xa = x[b,(8d-c2)%128], xb = x[b,(-8d-c2)%128], zero outside 32x32;
// xcomb[16-d] == xcomb[d]  =>  compute d=0..8, mirror-write 9..15.
// (Verified: r3 fp32 7.8e-3, r4..r7 bf16-MFMA 1.56e-2 vs np ref.)
//
// Round 8: weight A-fragments precomputed ONCE into d_ws by a 1-block prep
// kernel, lane-indexed so the main kernel reads them with 9 coalesced
// global b128 loads. Kills (a) the 4-way LDS bank conflicts on per-lane
// wf reads (r7 counter: 414,720 conflict cycles/dispatch — granule index
// 4c+q -> banks 16c mod 32), (b) the 18 gather wave-loads of wgt per block
// at the L1 port, (c) 9 KB LDS (21.7 KB left -> 7 blocks/CU resident).

typedef __attribute__((ext_vector_type(8))) short short8;
typedef __attribute__((ext_vector_type(4))) float floatx4;

#define NT 256
#define SROW 34              // xs row stride in 16-B granules
#define SOCT (10 * SROW)     // granules per c2-octet

static __device__ __forceinline__ short bf16bits(float f) {
    __hip_bfloat16 h = __float2bfloat16(f);
    return __builtin_bit_cast(short, h);
}

// wfrag[t*512 + lane*8 + j] = bf16(W[c][q*8+j][2-u][2-v]), t=u*3+v,
// c=lane&15, q=lane>>4.  4608 shorts = 9216 B in d_ws.
__global__ void prep_weights(const float* __restrict__ wgt,
                             short* __restrict__ wfrag) {
    const int tid = threadIdx.x;   // 256 threads, 18 vals each
#pragma unroll
    for (int it = 0; it < 18; ++it) {
        const int v    = tid + it * NT;      // 0..4607
        const int t    = v / 512;
        const int rem  = v & 511;
        const int lane = rem >> 3;
        const int j    = rem & 7;
        const int c    = lane & 15;
        const int q    = lane >> 4;
        const int u    = t / 3;
        const int vv   = t - 3 * u;
        wfrag[v] = bf16bits(wgt[((c * 32 + q * 8 + j) * 3 + (2 - u)) * 3 + (2 - vv)]);
    }
}

__global__ __launch_bounds__(NT, 4)
void fconv_mfma(const float* __restrict__ x,
                const short* __restrict__ wfrag,
                float* __restrict__ out) {
    __shared__ __align__(16) short xs[4 * 10 * SROW * 8];   // 21760 B

    const int quarter = blockIdx.x;   // 0..3 : 8-row band
    const int d       = blockIdx.y;   // 0..8
    const int b       = blockIdx.z;   // 0..15
    const int r0      = quarter * 8;
    const int tid     = threadIdx.x;
    const int dup     = ((d & 7) == 0);   // d==0 or d==8: xa == xb

    const float* xb_base = x + ((size_t)b << 17);   // b*128*1024

    // ---- A fragments: 9 coalesced b128 loads (issue early, overlap staging) ----
    const int lane = tid & 63;
    const int c    = lane & 15;     // A: n index; B/D: col (s offset)
    const int q    = lane >> 4;     // k-octet; D: row group (n = q*4+reg)
    const short8* wptr = (const short8*)wfrag;
    short8 af[9];
#pragma unroll
    for (int t = 0; t < 9; ++t)
        af[t] = wptr[t * 64 + lane];

    // ---- stage xcomb granules: 1280 tasks (oct, r, s) ----
#pragma unroll
    for (int it = 0; it < 5; ++it) {
        const int task = tid + it * NT;       // 0..1279
        const int oct  = task / 320;          // wave-uniform (320 % 64 == 0)
        const int rem  = task - oct * 320;
        const int r    = rem >> 5;            // 0..9
        const int s    = rem & 31;
        const int gr   = r0 + r;
        short8 g;
        if (gr < 32) {
            const int off = (gr << 5) + s;
#pragma unroll
            for (int j = 0; j < 8; ++j) {
                const int c2  = oct * 8 + j;
                const int c1a = (8 * d - c2) & 127;
                const float va = xb_base[(c1a << 10) + off];
                float v;
                if (dup) {
                    v = va;
                } else {
                    const int c1b = (-8 * d - c2) & 127;
                    const float vb = xb_base[(c1b << 10) + off];
                    v = 0.5f * (va + vb);
                }
                g[j] = bf16bits(v);
            }
        } else {
#pragma unroll
            for (int j = 0; j < 8; ++j) g[j] = 0;
        }
        *(short8*)&xs[(oct * SOCT + r * SROW + s) << 3] = g;
    }
    // s-apron (s = 32, 33) zeros
    if (tid < 80) {
        const int oct = tid / 20;
        const int rem = tid - oct * 20;
        const int r   = rem >> 1;
        const int s   = 32 + (rem & 1);
        short8 z = {0, 0, 0, 0, 0, 0, 0, 0};
        *(short8*)&xs[(oct * SOCT + r * SROW + s) << 3] = z;
    }

    __syncthreads();

    // ---- compute: wave w does 4 tiles (2 rows x 2 col-halves) ----
    const int w = tid >> 6;
#pragma unroll
    for (int i = 0; i < 4; ++i) {
        const int lr = 2 * w + (i >> 1);      // local output row 0..7
        const int s0 = (i & 1) << 4;          // 0 or 16
        floatx4 acc = {0.f, 0.f, 0.f, 0.f};
        const short* basep = &xs[(q * SOCT + lr * SROW + s0 + c) << 3];
#pragma unroll
        for (int u = 0; u < 3; ++u)
#pragma unroll
            for (int v = 0; v < 3; ++v) {
                const short8 bf = *(const short8*)(basep + ((u * SROW + v) << 3));
                acc = __builtin_amdgcn_mfma_f32_16x16x32_bf16(af[u * 3 + v], bf, acc, 0, 0, 0);
            }
        // D: col = c (s = s0+c), row = q*4+reg (n)
        float* op = out + (size_t)(((b * 256 + d * 16 + q * 4) * 32 + (r0 + lr)) * 32 + s0 + c);
        op[0]    = acc.x;
        op[1024] = acc.y;
        op[2048] = acc.z;
        op[3072] = acc.w;
        if (d >= 1 && d <= 7) {   // mirror channel group (16-d)
            float* op2 = out + (size_t)(((b * 256 + (16 - d) * 16 + q * 4) * 32 + (r0 + lr)) * 32 + s0 + c);
            op2[0]    = acc.x;
            op2[1024] = acc.y;
            op2[2048] = acc.z;
            op2[3072] = acc.w;
        }
    }
}

extern "C" void kernel_launch(void* const* d_in, const int* in_sizes, int n_in,
                              void* d_out, int out_size, void* d_ws, size_t ws_size,
                              hipStream_t stream) {
    const float* x   = (const float*)d_in[0];   // (16,128,32,32) fp32
    const float* wgt = (const float*)d_in[1];   // (16,32,3,3)   fp32
    float* out  = (float*)d_out;                // (16,256,32,32) fp32
    short* wfrag = (short*)d_ws;                // 9216 B of workspace
    (void)in_sizes; (void)n_in; (void)out_size; (void)ws_size;

    prep_weights<<<1, NT, 0, stream>>>(wgt, wfrag);

    dim3 grid(4, 9, 16);    // (quarter-band, d=0..8, b)
    fconv_mfma<<<grid, dim3(NT), 0, stream>>>(x, wfrag, out);
}

// Round 9
// 76.023 us; speedup vs baseline: 1.6041x; 1.0713x over previous
//
#include <hip/hip_runtime.h>
#include <hip/hip_bf16.h>

// FConv2d exact reduced form:
// out[b, d*16+n, r, s] =
//   0.5 * sum_{c2<32,u,v<3} W[n,c2,2-u,2-v] * (xa + xb)[r+u, s+v]
// xa = x[b,(8d-c2)%128], xb = x[b,(-8d-c2)%128], zero outside 32x32;
// xcomb[16-d] == xcomb[d]  =>  compute d=0..8, mirror-write 9..15.
// (Verified: r3 fp32 7.8e-3, r4..r8 bf16-MFMA 1.56e-2 vs np ref.)
//
// Round 9: staging vectorized — each task loads 8 channels as float4 pairs
// (16 vector loads per 4 granules, was 64 scalar) and transposes in
// registers to the c2-interleaved granules. Task decode = r fastest in
// phase + SROW=35 -> conflict-free ds_write_b128. wf stride 40 shorts ->
// af-read granule 5c+q conflict-free. Single kernel node (r8's prep node
// cost ~+4us of graph-replay overhead; weight path is ~free either way).

typedef __attribute__((ext_vector_type(8))) short short8;
typedef __attribute__((ext_vector_type(4))) float floatx4;

#define NT 256
#define SROW 35              // xs row stride in 16-B granules
#define SOCT (10 * SROW)     // granules per c2-octet

static __device__ __forceinline__ short bf16bits(float f) {
    __hip_bfloat16 h = __float2bfloat16(f);
    return __builtin_bit_cast(short, h);
}

__global__ __launch_bounds__(NT, 4)
void fconv_mfma(const float* __restrict__ x,
                const float* __restrict__ wgt,
                float* __restrict__ out) {
    __shared__ __align__(16) short xs[4 * SOCT * 8];   // 22400 B
    __shared__ __align__(16) short wf[9 * 640];        // 11520 B, [t][n*40+c2]

    const int quarter = blockIdx.x;   // 0..3 : 8-row band
    const int d       = blockIdx.y;   // 0..8
    const int b       = blockIdx.z;   // 0..15
    const int r0      = quarter * 8;
    const int tid     = threadIdx.x;
    const int dup     = ((d & 7) == 0);   // d==0 or d==8: xa == xb

    const float* xb_base = x + ((size_t)b << 17);   // b*128*1024

    // ---- weights -> LDS: wf[t][n*40+c2] = W[n][c2][flip(t)], t=8-k ----
#pragma unroll
    for (int pp = 0; pp < 2; ++pp) {
        const int p  = tid + pp * NT;      // 0..511
        const int n  = p >> 5;
        const int c2 = p & 31;
        const float* wb = wgt + (size_t)(n * 32 + c2) * 9;
#pragma unroll
        for (int k = 0; k < 9; ++k)
            wf[(8 - k) * 640 + n * 40 + c2] = bf16bits(wb[k]);
    }

    // ---- stage xcomb: task = (oct, r, sq) builds 4 granules ----
    // main rows 0..7: 256 tasks (1/thread); rows 8..9: 64 tasks (wave 0)
    {
        const int oct = tid >> 6;         // wave-uniform
        const int rem = tid & 63;
        const int sq  = rem >> 3;         // 0..7  (s-quad)
        const int r   = rem & 7;          // fastest in phase -> CF writes
        const int gr  = r0 + r;
        short8 g[4];
        if (gr < 32) {
            const float* base = xb_base + (gr << 5) + (sq << 2);
            float vals[8][4];
#pragma unroll
            for (int j = 0; j < 8; ++j) {
                const int c2  = oct * 8 + j;
                const int c1a = (8 * d - c2) & 127;
                float4 A = *(const float4*)(base + (c1a << 10));
                if (!dup) {
                    const int c1b = (-8 * d - c2) & 127;
                    const float4 B = *(const float4*)(base + (c1b << 10));
                    A.x = 0.5f * (A.x + B.x); A.y = 0.5f * (A.y + B.y);
                    A.z = 0.5f * (A.z + B.z); A.w = 0.5f * (A.w + B.w);
                }
                vals[j][0] = A.x; vals[j][1] = A.y;
                vals[j][2] = A.z; vals[j][3] = A.w;
            }
#pragma unroll
            for (int ss = 0; ss < 4; ++ss)
#pragma unroll
                for (int j = 0; j < 8; ++j) g[ss][j] = bf16bits(vals[j][ss]);
        } else {
#pragma unroll
            for (int ss = 0; ss < 4; ++ss)
#pragma unroll
                for (int j = 0; j < 8; ++j) g[ss][j] = 0;
        }
#pragma unroll
        for (int ss = 0; ss < 4; ++ss)
            *(short8*)&xs[(oct * SOCT + r * SROW + (sq << 2) + ss) << 3] = g[ss];
    }
    if (tid < 64) {   // rows 8..9
        const int oct = tid >> 4;
        const int rem = tid & 15;
        const int sq  = rem >> 1;
        const int r   = 8 + (rem & 1);
        const int gr  = r0 + r;
        short8 g[4];
        if (gr < 32) {
            const float* base = xb_base + (gr << 5) + (sq << 2);
            float vals[8][4];
#pragma unroll
            for (int j = 0; j < 8; ++j) {
                const int c2  = oct * 8 + j;
                const int c1a = (8 * d - c2) & 127;
                float4 A = *(const float4*)(base + (c1a << 10));
                if (!dup) {
                    const int c1b = (-8 * d - c2) & 127;
                    const float4 B = *(const float4*)(base + (c1b << 10));
                    A.x = 0.5f * (A.x + B.x); A.y = 0.5f * (A.y + B.y);
                    A.z = 0.5f * (A.z + B.z); A.w = 0.5f * (A.w + B.w);
                }
                vals[j][0] = A.x; vals[j][1] = A.y;
                vals[j][2] = A.z; vals[j][3] = A.w;
            }
#pragma unroll
            for (int ss = 0; ss < 4; ++ss)
#pragma unroll
                for (int j = 0; j < 8; ++j) g[ss][j] = bf16bits(vals[j][ss]);
        } else {
#pragma unroll
            for (int ss = 0; ss < 4; ++ss)
#pragma unroll
                for (int j = 0; j < 8; ++j) g[ss][j] = 0;
        }
#pragma unroll
        for (int ss = 0; ss < 4; ++ss)
            *(short8*)&xs[(oct * SOCT + r * SROW + (sq << 2) + ss) << 3] = g[ss];
    }
    // s-apron (s = 32, 33) zeros
    if (tid < 80) {
        const int oct = tid / 20;
        const int rem = tid - oct * 20;
        const int r   = rem >> 1;
        const int s   = 32 + (rem & 1);
        short8 z = {0, 0, 0, 0, 0, 0, 0, 0};
        *(short8*)&xs[(oct * SOCT + r * SROW + s) << 3] = z;
    }

    __syncthreads();

    // ---- A fragments: 9 conflict-free ds_read_b128 (granule 5c+q) ----
    const int lane = tid & 63;
    const int c    = lane & 15;     // A: n index; B/D: col (s offset)
    const int q    = lane >> 4;     // k-octet; D: row group (n = q*4+reg)
    short8 af[9];
#pragma unroll
    for (int t = 0; t < 9; ++t)
        af[t] = *(const short8*)&wf[t * 640 + c * 40 + q * 8];

    // ---- compute: wave w does 4 tiles (2 rows x 2 col-halves) ----
    const int w = tid >> 6;
#pragma unroll
    for (int i = 0; i < 4; ++i) {
        const int lr = 2 * w + (i >> 1);      // local output row 0..7
        const int s0 = (i & 1) << 4;          // 0 or 16
        floatx4 acc = {0.f, 0.f, 0.f, 0.f};
        const short* basep = &xs[(q * SOCT + lr * SROW + s0 + c) << 3];
#pragma unroll
        for (int u = 0; u < 3; ++u)
#pragma unroll
            for (int v = 0; v < 3; ++v) {
                const short8 bf = *(const short8*)(basep + ((u * SROW + v) << 3));
                acc = __builtin_amdgcn_mfma_f32_16x16x32_bf16(af[u * 3 + v], bf, acc, 0, 0, 0);
            }
        // D: col = c (s = s0+c), row = q*4+reg (n)
        float* op = out + (size_t)(((b * 256 + d * 16 + q * 4) * 32 + (r0 + lr)) * 32 + s0 + c);
        op[0]    = acc.x;
        op[1024] = acc.y;
        op[2048] = acc.z;
        op[3072] = acc.w;
        if (d >= 1 && d <= 7) {   // mirror channel group (16-d)
            float* op2 = out + (size_t)(((b * 256 + (16 - d) * 16 + q * 4) * 32 + (r0 + lr)) * 32 + s0 + c);
            op2[0]    = acc.x;
            op2[1024] = acc.y;
            op2[2048] = acc.z;
            op2[3072] = acc.w;
        }
    }
}

extern "C" void kernel_launch(void* const* d_in, const int* in_sizes, int n_in,
                              void* d_out, int out_size, void* d_ws, size_t ws_size,
                              hipStream_t stream) {
    const float* x   = (const float*)d_in[0];   // (16,128,32,32) fp32
    const float* wgt = (const float*)d_in[1];   // (16,32,3,3)   fp32
    float* out = (float*)d_out;                 // (16,256,32,32) fp32
    (void)in_sizes; (void)n_in; (void)out_size; (void)d_ws; (void)ws_size;

    dim3 grid(4, 9, 16);    // (quarter-band, d=0..8, b)
    fconv_mfma<<<grid, dim3(NT), 0, stream>>>(x, wgt, out);
}

// Round 10
// 71.942 us; speedup vs baseline: 1.6950x; 1.0567x over previous
//
#include <hip/hip_runtime.h>
#include <hip/hip_bf16.h>

// FConv2d exact reduced form:
// out[b, d*16+n, r, s] =
//   0.5 * sum_{c2<32,u,v<3} W[n,c2,2-u,2-v] * (xa + xb)[r+u, s+v]
// xa = x[b,(8d-c2)%128], xb = x[b,(-8d-c2)%128], zero outside 32x32;
// xcomb[16-d] == xcomb[d]  =>  compute d=0..8, mirror-write 9..15.
// (Verified: r3 fp32 7.8e-3, r4..r9 bf16-MFMA 1.56e-2 vs np ref.)
//
// Round 10: (a) grid 576 -> 1152 blocks (4-row bands): 4.5 blocks/CU,
// makespan imbalance 1.33x -> 1.11x; (b) packed __float22bfloat162_rn
// conversion (halves staging cvt VALU); (c) ds_write phase conflicts
// <=2-way (free, m136) via rem = sq*6+r decode at SROW=35.

typedef __attribute__((ext_vector_type(8))) short short8;
typedef __attribute__((ext_vector_type(4))) float floatx4;

#define NT 256
#define SROW 35              // xs row stride in 16-B granules
#define SOCT (6 * SROW)      // granules per c2-octet (6 staged rows)

__global__ __launch_bounds__(NT, 6)
void fconv_mfma(const float* __restrict__ x,
                const float* __restrict__ wgt,
                float* __restrict__ out) {
    __shared__ __align__(16) short xs[4 * SOCT * 8];   // 13440 B
    __shared__ __align__(16) short wf[9 * 640];        // 11520 B, [t][n*40+c2]

    const int band = blockIdx.x;      // 0..7 : 4-row band
    const int d    = blockIdx.y;      // 0..8
    const int b    = blockIdx.z;      // 0..15
    const int r0   = band * 4;
    const int tid  = threadIdx.x;
    const int dup  = ((d & 7) == 0);  // d==0 or d==8: xa == xb

    const float* xb_base = x + ((size_t)b << 17);   // b*128*1024

    // ---- weights -> LDS: wf[t][n*40+c2] = W[n][c2][flip(t)], t=8-k ----
#pragma unroll
    for (int pp = 0; pp < 2; ++pp) {
        const int p  = tid + pp * NT;      // 0..511
        const int n  = p >> 5;
        const int c2 = p & 31;
        const float* wb = wgt + (size_t)(n * 32 + c2) * 9;
#pragma unroll
        for (int k = 0; k < 9; ++k) {
            __hip_bfloat16 h = __float2bfloat16(wb[k]);
            wf[(8 - k) * 640 + n * 40 + c2] = __builtin_bit_cast(short, h);
        }
    }

    // ---- stage xcomb: 192 tasks (oct, sq, r), 4 granules each ----
    if (tid < 192) {
        const int oct = tid / 48;         // 0..3
        const int rem = tid - oct * 48;   // 0..47
        const int sq  = rem / 6;          // 0..7
        const int r   = rem - sq * 6;     // 0..5  (fastest -> <=2-way writes)
        const int gr  = r0 + r;
        short8 g[4];
        if (gr < 32) {
            const float* base = xb_base + (gr << 5) + (sq << 2);
            float vals[8][4];
#pragma unroll
            for (int j = 0; j < 8; ++j) {
                const int c2  = oct * 8 + j;
                const int c1a = (8 * d - c2) & 127;
                float4 A = *(const float4*)(base + (c1a << 10));
                if (!dup) {
                    const int c1b = (-8 * d - c2) & 127;
                    const float4 B = *(const float4*)(base + (c1b << 10));
                    A.x = 0.5f * (A.x + B.x); A.y = 0.5f * (A.y + B.y);
                    A.z = 0.5f * (A.z + B.z); A.w = 0.5f * (A.w + B.w);
                }
                vals[j][0] = A.x; vals[j][1] = A.y;
                vals[j][2] = A.z; vals[j][3] = A.w;
            }
#pragma unroll
            for (int ss = 0; ss < 4; ++ss) {
                union { __hip_bfloat162 h2[4]; short8 s8; } u;
#pragma unroll
                for (int jj = 0; jj < 4; ++jj)
                    u.h2[jj] = __float22bfloat162_rn(
                        make_float2(vals[2 * jj][ss], vals[2 * jj + 1][ss]));
                g[ss] = u.s8;
            }
        } else {
#pragma unroll
            for (int ss = 0; ss < 4; ++ss)
#pragma unroll
                for (int j = 0; j < 8; ++j) g[ss][j] = 0;
        }
#pragma unroll
        for (int ss = 0; ss < 4; ++ss)
            *(short8*)&xs[(oct * SOCT + r * SROW + (sq << 2) + ss) << 3] = g[ss];
    }
    // s-apron (s = 32, 33) zeros: 4 oct * 6 r * 2 s = 48 granules
    if (tid < 48) {
        const int oct = tid / 12;
        const int rem = tid - oct * 12;
        const int r   = rem >> 1;
        const int s   = 32 + (rem & 1);
        short8 z = {0, 0, 0, 0, 0, 0, 0, 0};
        *(short8*)&xs[(oct * SOCT + r * SROW + s) << 3] = z;
    }

    __syncthreads();

    // ---- A fragments: 9 conflict-free ds_read_b128 (granule 5c+q) ----
    const int lane = tid & 63;
    const int c    = lane & 15;     // A: n index; B/D: col (s offset)
    const int q    = lane >> 4;     // k-octet; D: row group (n = q*4+reg)
    short8 af[9];
#pragma unroll
    for (int t = 0; t < 9; ++t)
        af[t] = *(const short8*)&wf[t * 640 + c * 40 + q * 8];

    // ---- compute: wave w -> output row r0+w, 2 col-half tiles ----
    const int w = tid >> 6;
#pragma unroll
    for (int i = 0; i < 2; ++i) {
        const int s0 = i << 4;            // 0 or 16
        floatx4 acc = {0.f, 0.f, 0.f, 0.f};
        const short* basep = &xs[(q * SOCT + w * SROW + s0 + c) << 3];
#pragma unroll
        for (int u = 0; u < 3; ++u)
#pragma unroll
            for (int v = 0; v < 3; ++v) {
                const short8 bf = *(const short8*)(basep + ((u * SROW + v) << 3));
                acc = __builtin_amdgcn_mfma_f32_16x16x32_bf16(af[u * 3 + v], bf, acc, 0, 0, 0);
            }
        // D: col = c (s = s0+c), row = q*4+reg (n)
        float* op = out + (size_t)(((b * 256 + d * 16 + q * 4) * 32 + (r0 + w)) * 32 + s0 + c);
        op[0]    = acc.x;
        op[1024] = acc.y;
        op[2048] = acc.z;
        op[3072] = acc.w;
        if (d >= 1 && d <= 7) {   // mirror channel group (16-d)
            float* op2 = op + (size_t)(16 - 2 * d) * 16384;  // ((16-d)-d)*16*1024
            op2[0]    = acc.x;
            op2[1024] = acc.y;
            op2[2048] = acc.z;
            op2[3072] = acc.w;
        }
    }
}

extern "C" void kernel_launch(void* const* d_in, const int* in_sizes, int n_in,
                              void* d_out, int out_size, void* d_ws, size_t ws_size,
                              hipStream_t stream) {
    const float* x   = (const float*)d_in[0];   // (16,128,32,32) fp32
    const float* wgt = (const float*)d_in[1];   // (16,32,3,3)   fp32
    float* out = (float*)d_out;                 // (16,256,32,32) fp32
    (void)in_sizes; (void)n_in; (void)out_size; (void)d_ws; (void)ws_size;

    dim3 grid(8, 9, 16);    // (4-row band, d=0..8, b)
    fconv_mfma<<<grid, dim3(NT), 0, stream>>>(x, wgt, out);
}